// Round 10
// baseline (1398.491 us; speedup 1.0000x reference)
//
#include <hip/hip_runtime.h>
#include <hip/hip_fp16.h>
#include <math.h>

#define Q_ 13294
#define D_ 256
#define NLAYERS_ 6
#define MROWS 26588
#define MD ((size_t)MROWS * D_)

typedef unsigned short ushort_t;
typedef short bf16x8 __attribute__((ext_vector_type(8)));
typedef float f32x4 __attribute__((ext_vector_type(4)));
typedef ushort_t u16x8 __attribute__((ext_vector_type(8)));
typedef __fp16 fp16x2 __attribute__((ext_vector_type(2)));

__device__ __forceinline__ float u2f(ushort_t u) {
    return __uint_as_float(((unsigned)u) << 16);
}
__device__ __forceinline__ ushort_t f2bf(float f) {
    unsigned u = __float_as_uint(f);
    return (ushort_t)((u + 0x7fffu + ((u >> 16) & 1u)) >> 16);
}
__device__ __forceinline__ unsigned packh2(float a, float b) {
    fp16x2 t = __builtin_amdgcn_cvt_pkrtz(a, b);   // v_cvt_pkrtz_f16_f32: lo=a, hi=b
    union { fp16x2 h; unsigned u; } c; c.h = t; return c.u;
}
__device__ __forceinline__ ushort_t f2h(float f) {
    _Float16 hv = (_Float16)f;
    union { _Float16 h; ushort_t u; } c; c.h = hv; return c.u;
}
__device__ __forceinline__ __half2 uash2(unsigned u) {
    union { unsigned u; __half2 h; } c; c.u = u; return c.h;
}
__device__ __forceinline__ void decode_row(int gr, int& b, int& l, int& p) {
    b = (gr >= Q_) ? 1 : 0;
    int q = gr - b * Q_;
    if (q < 10000)      { l = 0; p = q; }
    else if (q < 12500) { l = 1; p = q - 10000; }
    else if (q < 13125) { l = 2; p = q - 12500; }
    else                { l = 3; p = q - 13125; }
}

// ---------------------------------------------------------------------------
// Flatten src (fp32 transpose): X[b, s_l+p, d] = src_l[b,d,p]; writes the
// persistent bf16 mirror Xb, and (fused-Tq mode) layer-0's query tile
// Tq = f2bf(x + pos + le) via a second transposed LDS tile for pos.
// grid (313, 8, 8), block (32,8)
// ---------------------------------------------------------------------------
__global__ __launch_bounds__(256)
void flatten_kernel(const float* __restrict__ s0, const float* __restrict__ s1,
                    const float* __restrict__ s2, const float* __restrict__ s3,
                    const float* __restrict__ p0_, const float* __restrict__ p1_,
                    const float* __restrict__ p2_, const float* __restrict__ p3_,
                    const float* __restrict__ le,
                    float* __restrict__ X, ushort_t* __restrict__ Xb,
                    ushort_t* __restrict__ Tq)
{
    const int lHW[4] = {10000, 2500, 625, 169};
    const int lS[4]  = {0, 10000, 12500, 13125};
    int z = blockIdx.z;
    int l = z & 3, b = z >> 2;
    int HW = lHW[l];
    int p0 = blockIdx.x * 32;
    if (p0 >= HW) return;
    int d0 = blockIdx.y * 32;
    const float* src = (l == 0) ? s0 : (l == 1) ? s1 : (l == 2) ? s2 : s3;
    const float* pos = (l == 0) ? p0_ : (l == 1) ? p1_ : (l == 2) ? p2_ : p3_;
    int tx = threadIdx.x, ty = threadIdx.y;
    __shared__ float t[32][33];
    __shared__ float tp[32][33];
    #pragma unroll
    for (int i = 0; i < 4; ++i) {
        int d = d0 + ty + 8 * i, p = p0 + tx;
        size_t sidx = (size_t)(b * D_ + d) * HW + p;
        t[ty + 8 * i][tx] = (p < HW) ? src[sidx] : 0.f;
        if (Tq) tp[ty + 8 * i][tx] = (p < HW) ? pos[sidx] : 0.f;
    }
    __syncthreads();
    #pragma unroll
    for (int i = 0; i < 4; ++i) {
        int p = p0 + ty + 8 * i, d = d0 + tx;
        if (p < HW) {
            float v = t[tx][ty + 8 * i];
            size_t idx = (size_t)(b * Q_ + lS[l] + p) * D_ + d;
            X[idx] = v;
            Xb[idx] = f2bf(v);
            if (Tq)
                Tq[idx] = f2bf(v + tp[tx][ty + 8 * i] + le[l * D_ + d]);
        }
    }
}

// ---------------------------------------------------------------------------
// PL precompute (one-time): PL[b, s_l+p, d] = pos_l[b,d,p] + le[l,d]  (fp32).
// Coalesced transpose via LDS.  grid (313, 8, 8), block (32,8)
// ---------------------------------------------------------------------------
__global__ __launch_bounds__(256)
void pl_kernel(const float* __restrict__ p0_, const float* __restrict__ p1_,
               const float* __restrict__ p2_, const float* __restrict__ p3_,
               const float* __restrict__ le, float* __restrict__ PL)
{
    const int lHW[4] = {10000, 2500, 625, 169};
    const int lS[4]  = {0, 10000, 12500, 13125};
    int z = blockIdx.z;
    int l = z & 3, b = z >> 2;
    int HW = lHW[l];
    int p0 = blockIdx.x * 32;
    if (p0 >= HW) return;
    int d0 = blockIdx.y * 32;
    const float* pos = (l == 0) ? p0_ : (l == 1) ? p1_ : (l == 2) ? p2_ : p3_;
    int tx = threadIdx.x, ty = threadIdx.y;
    __shared__ float t[32][33];
    #pragma unroll
    for (int i = 0; i < 4; ++i) {
        int d = d0 + ty + 8 * i, p = p0 + tx;
        t[ty + 8 * i][tx] = (p < HW) ? pos[(size_t)(b * D_ + d) * HW + p] : 0.f;
    }
    __syncthreads();
    #pragma unroll
    for (int i = 0; i < 4; ++i) {
        int p = p0 + ty + 8 * i, d = d0 + tx;
        if (p < HW)
            PL[(size_t)(b * Q_ + lS[l] + p) * D_ + d] =
                t[tx][ty + 8 * i] + le[l * D_ + d];
    }
}

// ---------------------------------------------------------------------------
// Weight transpose+convert for one layer: Wt[n][k](bf16) = W[k][n](fp32)
// Woff^T (256 rows) and Wattn^T (128 rows) adjacent -> combined [384][256].
// grid (256, 6), block (32,8).
// ---------------------------------------------------------------------------
__global__ __launch_bounds__(256)
void wconv_kernel(const float* __restrict__ Woff, const float* __restrict__ Wattn,
                  const float* __restrict__ Wv, const float* __restrict__ Wo,
                  const float* __restrict__ W1, const float* __restrict__ W2,
                  ushort_t* __restrict__ WBl)
{
    const int mk[6] = {256, 256, 256, 256, 256, 1024};
    const int mn[6] = {256, 128, 256, 256, 1024, 256};
    const int mo[6] = {0, 65536, 98304, 163840, 229376, 491520};
    int m = blockIdx.y;
    int K = mk[m], N = mn[m];
    int tilesN = N >> 5;
    int tiles = (K >> 5) * tilesN;
    int tid = blockIdx.x;
    if (tid >= tiles) return;
    int tk = tid / tilesN, tn = tid - tk * tilesN;
    const float* Wsrc = (m == 0) ? Woff : (m == 1) ? Wattn : (m == 2) ? Wv :
                        (m == 3) ? Wo : (m == 4) ? W1 : W2;
    ushort_t* dst = WBl + mo[m];
    __shared__ float t[32][33];
    int tx = threadIdx.x, ty = threadIdx.y;
    #pragma unroll
    for (int i = 0; i < 4; ++i) {
        int k = tk * 32 + ty + 8 * i, n = tn * 32 + tx;
        t[ty + 8 * i][tx] = Wsrc[(size_t)k * N + n];
    }
    __syncthreads();
    #pragma unroll
    for (int i = 0; i < 4; ++i) {
        int n = tn * 32 + ty + 8 * i, k = tk * 32 + tx;
        dst[(size_t)n * K + k] = f2bf(t[tx][ty + 8 * i]);
    }
}

// ---------------------------------------------------------------------------
// qmake (fallback when NC>1): Tq[r, d] = X + pos + le (bf16)
// ---------------------------------------------------------------------------
__global__ __launch_bounds__(256)
void qmake_kernel(const float* __restrict__ X,
                  const float* __restrict__ p0_, const float* __restrict__ p1_,
                  const float* __restrict__ p2_, const float* __restrict__ p3_,
                  const float* __restrict__ le,
                  ushort_t* __restrict__ Tq, int row0, int mc)
{
    const int lHW[4] = {10000, 2500, 625, 169};
    int gid = blockIdx.x * 256 + threadIdx.x;
    int r = gid >> 6, d4 = gid & 63;
    if (r >= mc) return;
    int gr = row0 + r;
    int b, l, p;
    decode_row(gr, b, l, p);
    const float* pos = (l == 0) ? p0_ : (l == 1) ? p1_ : (l == 2) ? p2_ : p3_;
    int HW = lHW[l];
    int d = d4 * 4;
    float4 xv = *(const float4*)(X + (size_t)gr * D_ + d);
    ushort4 o;
    o.x = f2bf(xv.x + pos[(size_t)(b * D_ + d + 0) * HW + p] + le[l * D_ + d + 0]);
    o.y = f2bf(xv.y + pos[(size_t)(b * D_ + d + 1) * HW + p] + le[l * D_ + d + 1]);
    o.z = f2bf(xv.z + pos[(size_t)(b * D_ + d + 2) * HW + p] + le[l * D_ + d + 2]);
    o.w = f2bf(xv.w + pos[(size_t)(b * D_ + d + 3) * HW + p] + le[l * D_ + d + 3]);
    *(ushort4*)(Tq + (size_t)r * D_ + d) = o;
}

// ---------------------------------------------------------------------------
// MFMA bf16 GEMM: C[M,N](ldc) = A[M,K](bf16) @ Wt^T + bias (Wt is [N][K]).
// Tile BM x 128, BK=64, 256 thr = 4 waves 2x2.  global_load_lds width=16,
// linear LDS.  Bijective XCD-chunked swizzle, column-fastest row panels.
// LDS-staged coalesced epilogue (two 64-col halves).
// CB=0: C fp32; CB=1: C bf16; CB=2: C f16.  fp32 residual, relu, dual bias.
// ---------------------------------------------------------------------------
template<int BM, int CB>
__global__ __launch_bounds__(256)
void gemm_b(const ushort_t* __restrict__ A, const ushort_t* __restrict__ Wt,
            const float* __restrict__ bias, const float* __restrict__ bias2,
            int nsplit, const float* __restrict__ Rres,
            void* __restrict__ Cp, int M, int K, int ldc, int relu)
{
    constexpr int AI = BM / 32;            // A-stage insts == A frag count
    constexpr int ES = (CB == 0) ? 4 : 2;  // output element size
    constexpr size_t STAGE_B = (size_t)(BM + 128) * 64 * 2;
    constexpr size_t CT_B = (size_t)BM * 64 * ES;   // per-half C tile
    constexpr size_t LDS_B = (STAGE_B > CT_B) ? STAGE_B : CT_B;
    __shared__ __align__(16) char lds[LDS_B];
    ushort_t* As = (ushort_t*)lds;
    ushort_t* Bs = (ushort_t*)lds + (size_t)BM * 64;
    int t = threadIdx.x;

    // XCD swizzle: orig dispatch id -> contiguous work chunk per XCD.
    int gx = gridDim.x, gy = gridDim.y;
    int nwg = gx * gy;
    int orig = blockIdx.y * gx + blockIdx.x;
    int qn = nwg >> 3, rn = nwg & 7;
    int xcd = orig & 7, idx = orig >> 3;
    int work = (xcd < rn ? xcd * (qn + 1) : rn * (qn + 1) + (xcd - rn) * qn) + idx;
    int bx = work / gy, by = work - bx * gy;   // column-fastest within row panel
    int m0 = bx * BM, n0 = by * 128;

    int w = t >> 6, lane = t & 63;
    int wm = (w & 1) * (BM / 2), wn = (w >> 1) * 64;
    int lm = lane & 15, quad = lane >> 4;
    f32x4 acc[AI][4] = {};

    int srow = lane >> 3;                 // 8 rows per wave-instruction
    int scol = (lane & 7) * 8;
    const ushort_t* Ab = A + (size_t)(m0 + w * (BM / 4) + srow) * K + scol;
    const ushort_t* Bb = Wt + (size_t)(n0 + w * 32 + srow) * K + scol;
    bool mfull = (m0 + BM <= M);

    for (int k0 = 0; k0 < K; k0 += 64) {
        if (mfull) {
            #pragma unroll
            for (int i = 0; i < AI; ++i)
                __builtin_amdgcn_global_load_lds(
                    (const void*)(Ab + (size_t)(i * 8) * K + k0),
                    (void*)&As[(w * (BM / 4) + i * 8) * 64], 16, 0, 0);
        } else {
            #pragma unroll
            for (int i = 0; i < AI; ++i)
                if (m0 + w * (BM / 4) + srow + i * 8 < M)
                    __builtin_amdgcn_global_load_lds(
                        (const void*)(Ab + (size_t)(i * 8) * K + k0),
                        (void*)&As[(w * (BM / 4) + i * 8) * 64], 16, 0, 0);
        }
        #pragma unroll
        for (int i = 0; i < 4; ++i)
            __builtin_amdgcn_global_load_lds(
                (const void*)(Bb + (size_t)(i * 8) * K + k0),
                (void*)&Bs[(w * 32 + i * 8) * 64], 16, 0, 0);
        __syncthreads();
        #pragma unroll
        for (int ks = 0; ks < 64; ks += 32) {
            bf16x8 af[AI], bfr[4];
            #pragma unroll
            for (int i = 0; i < AI; ++i)
                af[i] = *(const bf16x8*)&As[(wm + i * 16 + lm) * 64 + ks + quad * 8];
            #pragma unroll
            for (int j = 0; j < 4; ++j)
                bfr[j] = *(const bf16x8*)&Bs[(wn + j * 16 + lm) * 64 + ks + quad * 8];
            #pragma unroll
            for (int i = 0; i < AI; ++i)
                #pragma unroll
                for (int j = 0; j < 4; ++j)
                    acc[i][j] = __builtin_amdgcn_mfma_f32_16x16x32_bf16(
                        af[i], bfr[j], acc[i][j], 0, 0, 0);
        }
        __syncthreads();
    }

    // ---- LDS-staged coalesced epilogue (two 64-col halves) ----
    constexpr int CHUNKS = (int)(CT_B / 16);       // 16-B chunks per half
    constexpr int CPR = (64 * ES) / 16;            // chunks per row
    constexpr int EPC = 16 / ES;                   // elements per chunk
    int halfsel = w >> 1;                          // this wave's column half
    #pragma unroll
    for (int half = 0; half < 2; ++half) {
        __syncthreads();                           // LDS reuse guard
        if (halfsel == half) {
            #pragma unroll
            for (int i = 0; i < AI; ++i) {
                #pragma unroll
                for (int j = 0; j < 4; ++j) {
                    int col = j * 16 + lm;         // 0..63 within half
                    int gcol = n0 + half * 64 + col;
                    float bc = (gcol < nsplit) ? bias[gcol] : bias2[gcol - nsplit];
                    #pragma unroll
                    for (int r = 0; r < 4; ++r) {
                        int rloc = wm + i * 16 + quad * 4 + r;
                        float v = acc[i][j][r] + bc;
                        if (relu) v = fmaxf(v, 0.f);
                        if (CB == 0) ((float*)lds)[rloc * 64 + col] = v;
                        else if (CB == 1) ((ushort_t*)lds)[rloc * 64 + col] = f2bf(v);
                        else ((ushort_t*)lds)[rloc * 64 + col] = f2h(v);
                    }
                }
            }
        }
        __syncthreads();
        for (int c0 = t; c0 < CHUNKS; c0 += 256) {
            int row = c0 / CPR, cp = c0 - row * CPR;
            int grow = m0 + row;
            if (grow >= M) continue;
            int gcol = n0 + half * 64 + cp * EPC;
            if (CB == 0) {
                float4 f = *(const float4*)(lds + (size_t)c0 * 16);
                if (Rres) {
                    float4 rr = *(const float4*)(Rres + (size_t)grow * ldc + gcol);
                    f.x += rr.x; f.y += rr.y; f.z += rr.z; f.w += rr.w;
                }
                *(float4*)((float*)Cp + (size_t)grow * ldc + gcol) = f;
            } else {
                uint4 val = *(const uint4*)(lds + (size_t)c0 * 16);
                *(uint4*)((ushort_t*)Cp + (size_t)grow * ldc + gcol) = val;
            }
        }
    }
}

// ---------------------------------------------------------------------------
// Fused GEMM + residual + LayerNorm (+ optional next-layer Tq via PL table).
// C = LN(A @ Wt^T + bias + Rres) * g + b  -> X fp32, Xb bf16, Tq bf16.
// v2: tile 16 x 256, BK=32 -> 18 KB LDS -> 8 blocks/CU (was 4 @ 36.9 KB),
// grid 1662 (was 831) -> all blocks resident, latency hidden by TLP.
// 4 waves side by side in N; per-row mean/var via 16-lane shfl + 4-wave
// LDS reduce.  Wave 0 stages A (1 global_load_lds); each wave stages its
// own 64 B-rows (4 instrs).  Epilogue stages the normalized fp32 row-tile
// in LDS (stride 260) overlaying dead staging; coalesced 3-output copy.
// ---------------------------------------------------------------------------
__global__ __launch_bounds__(256)
void gemm_ln(const ushort_t* __restrict__ A, const ushort_t* __restrict__ Wt,
             const float* __restrict__ bias, const float* __restrict__ Rres,
             const float* __restrict__ g, const float* __restrict__ b,
             float* __restrict__ Xo, ushort_t* __restrict__ Xb,
             const float* __restrict__ PLf, ushort_t* __restrict__ Tq,
             int M, int K)
{
    __shared__ __align__(16) char lds[18048];
    ushort_t* As = (ushort_t*)lds;                  // [16][32] staging
    ushort_t* Bs = (ushort_t*)(lds + 1024);         // [256][32] staging
    float* Ct   = (float*)lds;                      // [16][260] epilogue tile
    float* psum = (float*)(lds + 17408);            // [4][16][2]
    float* mrs  = (float*)(lds + 17920);            // [16][2]

    int t = threadIdx.x;
    // 1D bijective XCD swizzle
    int nwg = gridDim.x, orig = blockIdx.x;
    int qn = nwg >> 3, rn = nwg & 7;
    int xcd = orig & 7, idx = orig >> 3;
    int work = (xcd < rn ? xcd * (qn + 1) : rn * (qn + 1) + (xcd - rn) * qn) + idx;
    int m0 = work * 16;

    int w = t >> 6, lane = t & 63;
    int lm = lane & 15, quad = lane >> 4;
    int colbase = w * 64;
    f32x4 acc[4] = {};

    int arow = lane >> 2;                 // 16 rows per wave-instruction
    int acol8 = lane & 3;
    const ushort_t* Abp = A + (size_t)(m0 + arow) * K + acol8 * 8;
    const ushort_t* Bbp = Wt + (size_t)(colbase + arow) * K + acol8 * 8;
    bool mfull = (m0 + 16 <= M);

    for (int k0 = 0; k0 < K; k0 += 32) {
        if (w == 0) {
            if (mfull) {
                __builtin_amdgcn_global_load_lds((const void*)(Abp + k0),
                    (void*)As, 16, 0, 0);
            } else if (m0 + arow < M) {
                __builtin_amdgcn_global_load_lds((const void*)(Abp + k0),
                    (void*)As, 16, 0, 0);
            }
        }
        #pragma unroll
        for (int i = 0; i < 4; ++i)
            __builtin_amdgcn_global_load_lds(
                (const void*)(Bbp + (size_t)(i * 16) * K + k0),
                (void*)&Bs[(colbase + i * 16) * 32], 16, 0, 0);
        __syncthreads();
        bf16x8 af = *(const bf16x8*)&As[lm * 32 + quad * 8];
        bf16x8 bfr[4];
        #pragma unroll
        for (int j = 0; j < 4; ++j)
            bfr[j] = *(const bf16x8*)&Bs[(colbase + j * 16 + lm) * 32 + quad * 8];
        #pragma unroll
        for (int j = 0; j < 4; ++j)
            acc[j] = __builtin_amdgcn_mfma_f32_16x16x32_bf16(
                af, bfr[j], acc[j], 0, 0, 0);
        __syncthreads();
    }

    // v = acc + bias + residual (in place)
    float bcol[4];
    #pragma unroll
    for (int j = 0; j < 4; ++j) bcol[j] = bias[colbase + j * 16 + lm];
    #pragma unroll
    for (int r = 0; r < 4; ++r) {
        int grow = m0 + quad * 4 + r;
        bool ok = grow < M;
        #pragma unroll
        for (int j = 0; j < 4; ++j) {
            float res = ok ? Rres[(size_t)grow * 256 + colbase + j * 16 + lm] : 0.f;
            acc[j][r] += bcol[j] + res;
        }
    }
    // per-row partial sums: sum over j (in-lane) then over lm (16-lane shfl)
    #pragma unroll
    for (int r = 0; r < 4; ++r) {
        float s = acc[0][r] + acc[1][r] + acc[2][r] + acc[3][r];
        float q = acc[0][r] * acc[0][r] + acc[1][r] * acc[1][r]
                + acc[2][r] * acc[2][r] + acc[3][r] * acc[3][r];
        #pragma unroll
        for (int m = 1; m <= 8; m <<= 1) {
            s += __shfl_xor(s, m, 64);
            q += __shfl_xor(q, m, 64);
        }
        if (lm == 0) {
            int row = quad * 4 + r;
            psum[(w * 16 + row) * 2 + 0] = s;
            psum[(w * 16 + row) * 2 + 1] = q;
        }
    }
    __syncthreads();
    if (t < 16) {
        float s = psum[t * 2] + psum[(16 + t) * 2] + psum[(32 + t) * 2] + psum[(48 + t) * 2];
        float q = psum[t * 2 + 1] + psum[(16 + t) * 2 + 1]
                + psum[(32 + t) * 2 + 1] + psum[(48 + t) * 2 + 1];
        float mean = s * (1.f / 256.f);
        float var = fmaxf(q * (1.f / 256.f) - mean * mean, 0.f);
        mrs[t * 2 + 0] = mean;
        mrs[t * 2 + 1] = rsqrtf(var + 1e-5f);
    }
    __syncthreads();
    // normalize into Ct (stride 260 floats: 16B-aligned, 2-way bank = free)
    float gc[4], bc2[4];
    #pragma unroll
    for (int j = 0; j < 4; ++j) {
        gc[j]  = g[colbase + j * 16 + lm];
        bc2[j] = b[colbase + j * 16 + lm];
    }
    #pragma unroll
    for (int r = 0; r < 4; ++r) {
        int row = quad * 4 + r;
        float mean = mrs[row * 2], rs = mrs[row * 2 + 1];
        #pragma unroll
        for (int j = 0; j < 4; ++j)
            Ct[row * 260 + colbase + j * 16 + lm] =
                (acc[j][r] - mean) * rs * gc[j] + bc2[j];
    }
    __syncthreads();
    // coalesced out: X fp32 + Xb bf16 (+ Tq bf16 via PL)
    for (int c0 = t; c0 < 16 * 64; c0 += 256) {
        int row = c0 >> 6, cp = c0 & 63;
        int grow = m0 + row;
        if (grow >= M) continue;
        float4 f = *(const float4*)&Ct[row * 260 + cp * 4];
        size_t gbase = (size_t)grow * 256 + cp * 4;
        *(float4*)(Xo + gbase) = f;
        ushort4 ob;
        ob.x = f2bf(f.x); ob.y = f2bf(f.y); ob.z = f2bf(f.z); ob.w = f2bf(f.w);
        *(ushort4*)(Xb + gbase) = ob;
        if (Tq) {
            float4 pl = *(const float4*)(PLf + gbase);
            ushort4 tq;
            tq.x = f2bf(f.x + pl.x); tq.y = f2bf(f.y + pl.y);
            tq.z = f2bf(f.z + pl.z); tq.w = f2bf(f.w + pl.w);
            *(ushort4*)(Tq + gbase) = tq;
        }
    }
}

// ---------------------------------------------------------------------------
// LayerNorm chunk (legacy fallback): X = LN(PRE)*g+b + Xb mirror (+ Tq).
// ---------------------------------------------------------------------------
__global__ __launch_bounds__(256)
void ln_kernel(const float* __restrict__ P, const float* __restrict__ g,
               const float* __restrict__ b, float* __restrict__ Xo,
               ushort_t* __restrict__ Xb,
               const float* __restrict__ PLf,
               const float* __restrict__ p0_, const float* __restrict__ p1_,
               const float* __restrict__ p2_, const float* __restrict__ p3_,
               const float* __restrict__ le, ushort_t* __restrict__ Tq,
               int row0, int mc)
{
    const int lHW[4] = {10000, 2500, 625, 169};
    int wave = threadIdx.x >> 6, lane = threadIdx.x & 63;
    int r = blockIdx.x * 4 + wave;
    if (r >= mc) return;
    const float* x = P + (size_t)r * D_;
    float4 v = *(const float4*)(x + lane * 4);
    float s = v.x + v.y + v.z + v.w;
    float sq = v.x * v.x + v.y * v.y + v.z * v.z + v.w * v.w;
    #pragma unroll
    for (int o = 32; o > 0; o >>= 1) {
        s += __shfl_xor(s, o, 64);
        sq += __shfl_xor(sq, o, 64);
    }
    float mean = s * (1.f / 256.f);
    float var = fmaxf(sq * (1.f / 256.f) - mean * mean, 0.f);
    float rs = rsqrtf(var + 1e-5f);
    float4 gv = *(const float4*)(g + lane * 4);
    float4 bv = *(const float4*)(b + lane * 4);
    float4 o;
    o.x = (v.x - mean) * rs * gv.x + bv.x;
    o.y = (v.y - mean) * rs * gv.y + bv.y;
    o.z = (v.z - mean) * rs * gv.z + bv.z;
    o.w = (v.w - mean) * rs * gv.w + bv.w;
    int gr = row0 + r;
    size_t base = (size_t)gr * D_ + lane * 4;
    *(float4*)(Xo + base) = o;
    ushort4 ob;
    ob.x = f2bf(o.x); ob.y = f2bf(o.y); ob.z = f2bf(o.z); ob.w = f2bf(o.w);
    *(ushort4*)(Xb + base) = ob;
    if (Tq) {
        ushort4 tq;
        if (PLf) {
            float4 pl = *(const float4*)(PLf + base);
            tq.x = f2bf(o.x + pl.x);
            tq.y = f2bf(o.y + pl.y);
            tq.z = f2bf(o.z + pl.z);
            tq.w = f2bf(o.w + pl.w);
        } else {
            int bb, l, p;
            decode_row(gr, bb, l, p);
            const float* pos = (l == 0) ? p0_ : (l == 1) ? p1_ : (l == 2) ? p2_ : p3_;
            int HW = lHW[l];
            int d = lane * 4;
            tq.x = f2bf(o.x + pos[(size_t)(bb * D_ + d + 0) * HW + p] + le[l * D_ + d + 0]);
            tq.y = f2bf(o.y + pos[(size_t)(bb * D_ + d + 1) * HW + p] + le[l * D_ + d + 1]);
            tq.z = f2bf(o.z + pos[(size_t)(bb * D_ + d + 2) * HW + p] + le[l * D_ + d + 2]);
            tq.w = f2bf(o.w + pos[(size_t)(bb * D_ + d + 3) * HW + p] + le[l * D_ + d + 3]);
        }
        *(ushort4*)(Tq + base) = tq;
    }
}

// ---------------------------------------------------------------------------
// Deformable sampling, v3: f16 packed math, 16B gathers, byte-offset
// descriptors, magic-div, XCD-chunked block swizzle, compact weight LDS.
// VAL is ONE contiguous [MROWS][256] **f16** buffer (global-row order).
// LOG row (ld 384, bf16): [0:256) offsets [h][pt][2], [256:384) attn [h][pt]
// ---------------------------------------------------------------------------
__global__ __launch_bounds__(256)
void sample_kernel(const ushort_t* __restrict__ LOG,
                   const ushort_t* __restrict__ VAL,
                   ushort_t* __restrict__ OUT, int row0, int mc)
{
    const int lW[4] = {100, 50, 25, 13};
    const int lS[4] = {0, 10000, 12500, 13125};
    const float invW[4] = {0.01f, 0.02f, 0.04f, 0.076923076923f};
    const unsigned mulM[4] = {5243u, 5243u, 5243u, 5042u};
    const int mulS[4] = {19, 18, 17, 16};

    __shared__ unsigned offs[8 * 8 * 68];   // stride 68 words per (row,head)
    __shared__ unsigned wts[8 * 8 * 36];    // stride 36 words (16B-aligned)

    int tid = threadIdx.x;

    // bijective XCD-chunked swizzle (m204): contiguous row band per XCD
    int nb = gridDim.x, bid = blockIdx.x;
    int xcd = bid & 7, idx = bid >> 3;
    int qc = nb >> 3, rc = nb & 7;
    int swz = (xcd < rc ? xcd * (qc + 1) : rc * (qc + 1) + (xcd - rc) * qc) + idx;
    int brow0 = swz * 8;

    // ---- stage 1: descriptors (4 iterations x 2 rows) ----
    #pragma unroll
    for (int it = 0; it < 4; ++it) {
        int rr = it * 2 + (tid >> 7);
        int j  = tid & 127;
        int h  = j >> 4, pt = j & 15;
        int r  = brow0 + rr;
        bool ok = (r < mc);
        int gr = row0 + (ok ? r : 0);
        int b, lq, p;
        decode_row(gr, b, lq, p);
        unsigned prow = ((unsigned)p * mulM[lq]) >> mulS[lq];   // exact p/W
        int pcol = p - (int)prow * lW[lq];
        float refx = (pcol + 0.5f) * invW[lq];
        float refy = ((float)prow + 0.5f) * invW[lq];

        const ushort_t* lg = LOG + (size_t)r * 384;
        float logit = ok ? u2f(lg[256 + h * 16 + pt]) : 0.f;
        float mx = logit;
        #pragma unroll
        for (int o = 8; o > 0; o >>= 1) mx = fmaxf(mx, __shfl_xor(mx, o, 16));
        float e = __expf(logit - mx);
        float ssum = e;
        #pragma unroll
        for (int o = 8; o > 0; o >>= 1) ssum += __shfl_xor(ssum, o, 16);
        float a = e / ssum;

        int l = pt >> 2;
        int Wl = lW[l];
        float ox = ok ? u2f(lg[h * 32 + pt * 2 + 0]) : 0.f;
        float oy = ok ? u2f(lg[h * 32 + pt * 2 + 1]) : 0.f;
        // (ref + off/W)*W - 0.5 == ref*W + off - 0.5
        float xf = refx * (float)Wl + ox - 0.5f;
        float yf = refy * (float)Wl + oy - 0.5f;
        xf = fmaxf(fminf(xf, 1.0e6f), -1.0e6f);
        yf = fmaxf(fminf(yf, 1.0e6f), -1.0e6f);
        float x0f = floorf(xf), y0f = floorf(yf);
        float fx = xf - x0f, fy = yf - y0f;
        int x0 = (int)x0f, y0 = (int)y0f;
        int x1 = x0 + 1, y1 = y0 + 1;
        int x0c = min(max(x0, 0), Wl - 1), x1c = min(max(x1, 0), Wl - 1);
        int y0c = min(max(y0, 0), Wl - 1), y1c = min(max(y1, 0), Wl - 1);
        float vx0 = (x0 >= 0 && x0 < Wl) ? 1.f : 0.f;
        float vx1 = (x1 >= 0 && x1 < Wl) ? 1.f : 0.f;
        float vy0 = (y0 >= 0 && y0 < Wl) ? 1.f : 0.f;
        float vy1 = (y1 >= 0 && y1 < Wl) ? 1.f : 0.f;
        // byte offsets: pixel stride 512B, head slice 64B
        unsigned base_b = ((unsigned)(b * Q_ + lS[l]) * 256u + (unsigned)(h * 32)) * 2u;
        int di = (rr * 8 + h) * 68 + pt * 4;
        uint4 ov;
        ov.x = base_b + (unsigned)(y0c * Wl + x0c) * 512u;
        ov.y = base_b + (unsigned)(y0c * Wl + x1c) * 512u;
        ov.z = base_b + (unsigned)(y1c * Wl + x0c) * 512u;
        ov.w = base_b + (unsigned)(y1c * Wl + x1c) * 512u;
        *(uint4*)&offs[di] = ov;
        int dw = (rr * 8 + h) * 36 + pt * 2;
        uint2 wv;
        wv.x = packh2(a * (1.f - fx) * (1.f - fy) * vx0 * vy0,
                      a * fx * (1.f - fy) * vx1 * vy0);
        wv.y = packh2(a * (1.f - fx) * fy * vx0 * vy1,
                      a * fx * fy * vx1 * vy1);
        *(uint2*)&wts[dw] = wv;
    }
    __syncthreads();

    // ---- stage 2: 32 threads/row, 16B gathers, pk_fma_f16 ----
    int r8 = tid >> 5;
    int r = brow0 + r8;
    if (r >= mc) return;
    int h = (tid >> 2) & 7;
    int cw = tid & 3;
    int dbase = (r8 * 8 + h) * 68;
    int dbw   = (r8 * 8 + h) * 36;
    const char* Vb = (const char*)VAL + cw * 16;

    __half2 a0 = __float2half2_rn(0.f), a1 = a0, a2 = a0, a3 = a0;
    #pragma unroll
    for (int g = 0; g < 8; ++g) {
        uint4 oA = *(const uint4*)&offs[dbase + g * 8 + 0];
        uint4 oB = *(const uint4*)&offs[dbase + g * 8 + 4];
        uint4 wp = *(const uint4*)&wts[dbw + g * 4];
        uint4 hv[8];
        hv[0] = *(const uint4*)(Vb + oA.x);
        hv[1] = *(const uint4*)(Vb + oA.y);
        hv[2] = *(const uint4*)(Vb + oA.z);
        hv[3] = *(const uint4*)(Vb + oA.w);
        hv[4] = *(const uint4*)(Vb + oB.x);
        hv[5] = *(const uint4*)(Vb + oB.y);
        hv[6] = *(const uint4*)(Vb + oB.z);
        hv[7] = *(const uint4*)(Vb + oB.w);
        __half2 w01 = uash2(wp.x), w23 = uash2(wp.y);
        __half2 w45 = uash2(wp.z), w67 = uash2(wp.w);
        __half2 we[8] = { __low2half2(w01), __high2half2(w01),
                          __low2half2(w23), __high2half2(w23),
                          __low2half2(w45), __high2half2(w45),
                          __low2half2(w67), __high2half2(w67) };
        #pragma unroll
        for (int jj = 0; jj < 8; ++jj) {
            a0 = __hfma2(uash2(hv[jj].x), we[jj], a0);
            a1 = __hfma2(uash2(hv[jj].y), we[jj], a1);
            a2 = __hfma2(uash2(hv[jj].z), we[jj], a2);
            a3 = __hfma2(uash2(hv[jj].w), we[jj], a3);
        }
    }
    float2 f0 = __half22float2(a0), f1 = __half22float2(a1);
    float2 f2v = __half22float2(a2), f3 = __half22float2(a3);
    u16x8 o;
    o[0] = f2bf(f0.x);  o[1] = f2bf(f0.y);
    o[2] = f2bf(f1.x);  o[3] = f2bf(f1.y);
    o[4] = f2bf(f2v.x); o[5] = f2bf(f2v.y);
    o[6] = f2bf(f3.x);  o[7] = f2bf(f3.y);
    *(u16x8*)(OUT + (size_t)r * D_ + h * 32 + cw * 8) = o;
}

extern "C" void kernel_launch(void* const* d_in, const int* in_sizes, int n_in,
                              void* d_out, int out_size, void* d_ws, size_t ws_size,
                              hipStream_t stream)
{
    // setup_inputs() dict order interleaves src/pos (sizes pair up).
    bool interleaved = (in_sizes[0] == in_sizes[1]);
    int si[4], pi[4];
    for (int i = 0; i < 4; ++i) {
        si[i] = interleaved ? 2 * i : i;
        pi[i] = interleaved ? 2 * i + 1 : 4 + i;
    }
    const float* src0 = (const float*)d_in[si[0]];
    const float* src1 = (const float*)d_in[si[1]];
    const float* src2 = (const float*)d_in[si[2]];
    const float* src3 = (const float*)d_in[si[3]];
    const float* pos0 = (const float*)d_in[pi[0]];
    const float* pos1 = (const float*)d_in[pi[1]];
    const float* pos2 = (const float*)d_in[pi[2]];
    const float* pos3 = (const float*)d_in[pi[3]];
    const float* level_embed = (const float*)d_in[8];
    const float* Woff  = (const float*)d_in[9];
    const float* boff  = (const float*)d_in[10];
    const float* Wattn = (const float*)d_in[11];
    const float* battn = (const float*)d_in[12];
    const float* Wv = (const float*)d_in[13];
    const float* bv = (const float*)d_in[14];
    const float* Wo = (const float*)d_in[15];
    const float* bo = (const float*)d_in[16];
    const float* g1 = (const float*)d_in[17];
    const float* b1 = (const float*)d_in[18];
    const float* W1  = (const float*)d_in[19];
    const float* bb1 = (const float*)d_in[20];
    const float* W2  = (const float*)d_in[21];
    const float* bb2 = (const float*)d_in[22];
    const float* g2 = (const float*)d_in[23];
    const float* b2 = (const float*)d_in[24];

    // VAL (f16, [MROWS][256] contiguous) lives in src0's buffer (consumed
    // after flatten; 20.5 MB capacity >= 13.6 MB). Harness restores inputs.
    ushort_t* VAL = (ushort_t*)d_in[si[0]];

    // X (fp32 state) lives in d_out; the final LN writes the output in place.
    float* X = (float*)d_out;

    const int WV_T = 98304, WO_T = 163840, W1_T = 229376, W2_T = 491520;
    const size_t WB_ELEMS = 753664;   // Woff^T+Wattn^T combined block at 0

    // ws = WB (1.507 MB) + Xb bf16 mirror (13.6 MB) + chunk region R +
    // optional PL fp32 table (27.2 MB, gated on ws_size).
    const int cand[9] = {1, 2, 4, 8, 16, 32, 64, 128, 256};
    int NC = 256;
    for (int i = 0; i < 9; ++i) {
        int rc = (MROWS + cand[i] - 1) / cand[i];
        size_t need = WB_ELEMS * 2 + MD * 2 + (size_t)rc * 3072 + 1024;
        if (need <= ws_size) { NC = cand[i]; break; }
    }
    const int RC = (MROWS + NC - 1) / NC;
    const bool fused_tq = (NC == 1);
    const size_t base_need = WB_ELEMS * 2 + MD * 2 + (size_t)RC * 3072 + 1024;
    const bool use_pl = fused_tq && (base_need + MD * 4 <= ws_size);
    const bool full_fuse = use_pl;   // gemm_ln path (needs PL for Tq emission)

    ushort_t* WBl  = (ushort_t*)d_ws;
    ushort_t* Xb   = (ushort_t*)((char*)d_ws + WB_ELEMS * 2);
    char* Rbase    = (char*)d_ws + WB_ELEMS * 2 + MD * 2;
    ushort_t* Tqu  = (ushort_t*)Rbase;
    ushort_t* LOGc = (ushort_t*)(Rbase + (size_t)RC * 512);
    float* PRE     = (float*)(Rbase + (size_t)RC * 2048);
    ushort_t* H1u  = (ushort_t*)Rbase;
    // In full_fuse, next-layer Tq goes to the (dead) PRE region, NOT Tqu:
    // fused FFN2 reads H1u (which overlays Tqu) while emitting Tq.
    ushort_t* Tq2  = (ushort_t*)(Rbase + (size_t)RC * 2048);
    float* PLf     = use_pl ? (float*)(Rbase + (size_t)RC * 3072) : nullptr;

    flatten_kernel<<<dim3(313, 8, 8), dim3(32, 8), 0, stream>>>(
        src0, src1, src2, src3, pos0, pos1, pos2, pos3, level_embed,
        X, Xb, fused_tq ? Tqu : nullptr);
    if (use_pl)
        pl_kernel<<<dim3(313, 8, 8), dim3(32, 8), 0, stream>>>(
            pos0, pos1, pos2, pos3, level_embed, PLf);

    const int BIG = 1 << 30;
    const int GLN = (MROWS + 15) / 16;

    for (int l = 0; l < NLAYERS_; ++l) {
        const float* Woff_l  = Woff  + (size_t)l * D_ * 256;
        const float* boff_l  = boff  + (size_t)l * 256;
        const float* Wattn_l = Wattn + (size_t)l * D_ * 128;
        const float* battn_l = battn + (size_t)l * 128;
        const float* Wv_l = Wv + (size_t)l * D_ * D_;
        const float* bv_l = bv + (size_t)l * D_;
        const float* Wo_l = Wo + (size_t)l * D_ * D_;
        const float* bo_l = bo + (size_t)l * D_;
        const float* g1_l = g1 + (size_t)l * D_;
        const float* b1_l = b1 + (size_t)l * D_;
        const float* W1_l  = W1  + (size_t)l * D_ * 1024;
        const float* bb1_l = bb1 + (size_t)l * 1024;
        const float* W2_l  = W2  + (size_t)l * 1024 * D_;
        const float* bb2_l = bb2 + (size_t)l * D_;
        const float* g2_l = g2 + (size_t)l * D_;
        const float* b2_l = b2 + (size_t)l * D_;

        wconv_kernel<<<dim3(256, 6), dim3(32, 8), 0, stream>>>(
            Woff_l, Wattn_l, Wv_l, Wo_l, W1_l, W2_l, WBl);

        // VAL = X @ Wv + bv : thin-N (256) -> BM=64, f16 output
        gemm_b<64, 2><<<dim3((MROWS + 63) / 64, 2), 256, 0, stream>>>(
            Xb, WBl + WV_T, bv_l, nullptr, BIG, nullptr, VAL, MROWS, 256, 256, 0);

        // attention, chunked
        for (int c = 0; c < NC; ++c) {
            int row0 = c * RC;
            int mc = MROWS - row0; if (mc > RC) mc = RC;
            if (mc <= 0) break;
            if (!fused_tq)
                qmake_kernel<<<(mc * 64 + 255) / 256, 256, 0, stream>>>(
                    X, pos0, pos1, pos2, pos3, level_embed, Tqu, row0, mc);
            // query location: layer 0 from flatten (Tqu); later layers from
            // the fused ln2 (Tq2) in full_fuse mode, else Tqu.
            const ushort_t* Qcur = (full_fuse && l > 0) ? Tq2 : Tqu;
            gemm_b<64, 1><<<dim3((mc + 63) / 64, 3), 256, 0, stream>>>(
                Qcur, WBl, boff_l, battn_l, 256, nullptr, LOGc, mc, 256, 384, 0);
            sample_kernel<<<(mc + 7) / 8, 256, 0, stream>>>(
                LOGc, VAL, Tqu, row0, mc);
            if (full_fuse) {
                // Wo GEMM + residual + ln1 fused (no Tq)
                gemm_ln<<<GLN, 256, 0, stream>>>(
                    Tqu, WBl + WO_T, bo_l, X, g1_l, b1_l, X, Xb,
                    nullptr, nullptr, MROWS, 256);
            } else {
                gemm_b<64, 0><<<dim3((mc + 63) / 64, 2), 256, 0, stream>>>(
                    Tqu, WBl + WO_T, bo_l, nullptr, BIG,
                    X + (size_t)row0 * D_, PRE, mc, 256, 256, 0);
                ln_kernel<<<(mc + 3) / 4, 256, 0, stream>>>(
                    PRE, g1_l, b1_l, X, Xb, nullptr,
                    pos0, pos1, pos2, pos3, level_embed, (ushort_t*)nullptr,
                    row0, mc);
            }
        }

        // FFN, chunked (H1u overlays Tqu/LOG; Tq2/PRE disjoint)
        for (int c = 0; c < NC; ++c) {
            int row0 = c * RC;
            int mc = MROWS - row0; if (mc > RC) mc = RC;
            if (mc <= 0) break;
            float* Xc = X + (size_t)row0 * D_;
            // FFN1: N=1024 wide -> keep BM=128 (grid already large)
            gemm_b<128, 1><<<dim3((mc + 127) / 128, 8), 256, 0, stream>>>(
                Xb + (size_t)row0 * D_, WBl + W1_T, bb1_l, nullptr, BIG,
                nullptr, H1u, mc, 256, 1024, 1);
            if (full_fuse) {
                // FFN2 + residual + ln2 fused; emits next-layer Tq into Tq2
                ushort_t* TqNext = (l < NLAYERS_ - 1) ? Tq2 : nullptr;
                gemm_ln<<<GLN, 256, 0, stream>>>(
                    H1u, WBl + W2_T, bb2_l, X, g2_l, b2_l, X, Xb,
                    PLf, TqNext, MROWS, 1024);
            } else {
                gemm_b<64, 0><<<dim3((mc + 63) / 64, 2), 256, 0, stream>>>(
                    H1u, WBl + W2_T, bb2_l, nullptr, BIG, Xc, PRE, mc, 1024, 256, 0);
                ushort_t* TqNext = (fused_tq && l < NLAYERS_ - 1) ? Tqu : nullptr;
                ln_kernel<<<(mc + 3) / 4, 256, 0, stream>>>(
                    PRE, g2_l, b2_l, X, Xb, PLf,
                    pos0, pos1, pos2, pos3, level_embed, TqNext,
                    row0, mc);
            }
        }
    }
}

// Round 11
// 1200.784 us; speedup vs baseline: 1.1646x; 1.1646x over previous
//
#include <hip/hip_runtime.h>
#include <hip/hip_fp16.h>
#include <math.h>

#define Q_ 13294
#define D_ 256
#define NLAYERS_ 6
#define MROWS 26588
#define MD ((size_t)MROWS * D_)

typedef unsigned short ushort_t;
typedef short bf16x8 __attribute__((ext_vector_type(8)));
typedef float f32x4 __attribute__((ext_vector_type(4)));
typedef ushort_t u16x8 __attribute__((ext_vector_type(8)));
typedef __fp16 fp16x2 __attribute__((ext_vector_type(2)));

__device__ __forceinline__ float u2f(ushort_t u) {
    return __uint_as_float(((unsigned)u) << 16);
}
__device__ __forceinline__ ushort_t f2bf(float f) {
    unsigned u = __float_as_uint(f);
    return (ushort_t)((u + 0x7fffu + ((u >> 16) & 1u)) >> 16);
}
__device__ __forceinline__ unsigned packh2(float a, float b) {
    fp16x2 t = __builtin_amdgcn_cvt_pkrtz(a, b);   // v_cvt_pkrtz_f16_f32: lo=a, hi=b
    union { fp16x2 h; unsigned u; } c; c.h = t; return c.u;
}
__device__ __forceinline__ ushort_t f2h(float f) {
    _Float16 hv = (_Float16)f;
    union { _Float16 h; ushort_t u; } c; c.h = hv; return c.u;
}
__device__ __forceinline__ __half2 uash2(unsigned u) {
    union { unsigned u; __half2 h; } c; c.u = u; return c.h;
}
__device__ __forceinline__ void decode_row(int gr, int& b, int& l, int& p) {
    b = (gr >= Q_) ? 1 : 0;
    int q = gr - b * Q_;
    if (q < 10000)      { l = 0; p = q; }
    else if (q < 12500) { l = 1; p = q - 10000; }
    else if (q < 13125) { l = 2; p = q - 12500; }
    else                { l = 3; p = q - 13125; }
}

// ---------------------------------------------------------------------------
// Flatten src (fp32 transpose): X[b, s_l+p, d] = src_l[b,d,p]; writes the
// persistent bf16 mirror Xb, and (fused-Tq mode) layer-0's query tile
// Tq = f2bf(x + pos + le) via a second transposed LDS tile for pos.
// grid (313, 8, 8), block (32,8)
// ---------------------------------------------------------------------------
__global__ __launch_bounds__(256)
void flatten_kernel(const float* __restrict__ s0, const float* __restrict__ s1,
                    const float* __restrict__ s2, const float* __restrict__ s3,
                    const float* __restrict__ p0_, const float* __restrict__ p1_,
                    const float* __restrict__ p2_, const float* __restrict__ p3_,
                    const float* __restrict__ le,
                    float* __restrict__ X, ushort_t* __restrict__ Xb,
                    ushort_t* __restrict__ Tq)
{
    const int lHW[4] = {10000, 2500, 625, 169};
    const int lS[4]  = {0, 10000, 12500, 13125};
    int z = blockIdx.z;
    int l = z & 3, b = z >> 2;
    int HW = lHW[l];
    int p0 = blockIdx.x * 32;
    if (p0 >= HW) return;
    int d0 = blockIdx.y * 32;
    const float* src = (l == 0) ? s0 : (l == 1) ? s1 : (l == 2) ? s2 : s3;
    const float* pos = (l == 0) ? p0_ : (l == 1) ? p1_ : (l == 2) ? p2_ : p3_;
    int tx = threadIdx.x, ty = threadIdx.y;
    __shared__ float t[32][33];
    __shared__ float tp[32][33];
    #pragma unroll
    for (int i = 0; i < 4; ++i) {
        int d = d0 + ty + 8 * i, p = p0 + tx;
        size_t sidx = (size_t)(b * D_ + d) * HW + p;
        t[ty + 8 * i][tx] = (p < HW) ? src[sidx] : 0.f;
        if (Tq) tp[ty + 8 * i][tx] = (p < HW) ? pos[sidx] : 0.f;
    }
    __syncthreads();
    #pragma unroll
    for (int i = 0; i < 4; ++i) {
        int p = p0 + ty + 8 * i, d = d0 + tx;
        if (p < HW) {
            float v = t[tx][ty + 8 * i];
            size_t idx = (size_t)(b * Q_ + lS[l] + p) * D_ + d;
            X[idx] = v;
            Xb[idx] = f2bf(v);
            if (Tq)
                Tq[idx] = f2bf(v + tp[tx][ty + 8 * i] + le[l * D_ + d]);
        }
    }
}

// ---------------------------------------------------------------------------
// PL precompute (one-time): PL[b, s_l+p, d] = pos_l[b,d,p] + le[l,d]  (fp32).
// Coalesced transpose via LDS.  grid (313, 8, 8), block (32,8)
// ---------------------------------------------------------------------------
__global__ __launch_bounds__(256)
void pl_kernel(const float* __restrict__ p0_, const float* __restrict__ p1_,
               const float* __restrict__ p2_, const float* __restrict__ p3_,
               const float* __restrict__ le, float* __restrict__ PL)
{
    const int lHW[4] = {10000, 2500, 625, 169};
    const int lS[4]  = {0, 10000, 12500, 13125};
    int z = blockIdx.z;
    int l = z & 3, b = z >> 2;
    int HW = lHW[l];
    int p0 = blockIdx.x * 32;
    if (p0 >= HW) return;
    int d0 = blockIdx.y * 32;
    const float* pos = (l == 0) ? p0_ : (l == 1) ? p1_ : (l == 2) ? p2_ : p3_;
    int tx = threadIdx.x, ty = threadIdx.y;
    __shared__ float t[32][33];
    #pragma unroll
    for (int i = 0; i < 4; ++i) {
        int d = d0 + ty + 8 * i, p = p0 + tx;
        t[ty + 8 * i][tx] = (p < HW) ? pos[(size_t)(b * D_ + d) * HW + p] : 0.f;
    }
    __syncthreads();
    #pragma unroll
    for (int i = 0; i < 4; ++i) {
        int p = p0 + ty + 8 * i, d = d0 + tx;
        if (p < HW)
            PL[(size_t)(b * Q_ + lS[l] + p) * D_ + d] =
                t[tx][ty + 8 * i] + le[l * D_ + d];
    }
}

// ---------------------------------------------------------------------------
// Weight transpose+convert for one layer: Wt[n][k](bf16) = W[k][n](fp32)
// Woff^T (256 rows) and Wattn^T (128 rows) adjacent -> combined [384][256].
// grid (256, 6), block (32,8).
// ---------------------------------------------------------------------------
__global__ __launch_bounds__(256)
void wconv_kernel(const float* __restrict__ Woff, const float* __restrict__ Wattn,
                  const float* __restrict__ Wv, const float* __restrict__ Wo,
                  const float* __restrict__ W1, const float* __restrict__ W2,
                  ushort_t* __restrict__ WBl)
{
    const int mk[6] = {256, 256, 256, 256, 256, 1024};
    const int mn[6] = {256, 128, 256, 256, 1024, 256};
    const int mo[6] = {0, 65536, 98304, 163840, 229376, 491520};
    int m = blockIdx.y;
    int K = mk[m], N = mn[m];
    int tilesN = N >> 5;
    int tiles = (K >> 5) * tilesN;
    int tid = blockIdx.x;
    if (tid >= tiles) return;
    int tk = tid / tilesN, tn = tid - tk * tilesN;
    const float* Wsrc = (m == 0) ? Woff : (m == 1) ? Wattn : (m == 2) ? Wv :
                        (m == 3) ? Wo : (m == 4) ? W1 : W2;
    ushort_t* dst = WBl + mo[m];
    __shared__ float t[32][33];
    int tx = threadIdx.x, ty = threadIdx.y;
    #pragma unroll
    for (int i = 0; i < 4; ++i) {
        int k = tk * 32 + ty + 8 * i, n = tn * 32 + tx;
        t[ty + 8 * i][tx] = Wsrc[(size_t)k * N + n];
    }
    __syncthreads();
    #pragma unroll
    for (int i = 0; i < 4; ++i) {
        int n = tn * 32 + ty + 8 * i, k = tk * 32 + tx;
        dst[(size_t)n * K + k] = f2bf(t[tx][ty + 8 * i]);
    }
}

// ---------------------------------------------------------------------------
// qmake (fallback when NC>1): Tq[r, d] = X + pos + le (bf16)
// ---------------------------------------------------------------------------
__global__ __launch_bounds__(256)
void qmake_kernel(const float* __restrict__ X,
                  const float* __restrict__ p0_, const float* __restrict__ p1_,
                  const float* __restrict__ p2_, const float* __restrict__ p3_,
                  const float* __restrict__ le,
                  ushort_t* __restrict__ Tq, int row0, int mc)
{
    const int lHW[4] = {10000, 2500, 625, 169};
    int gid = blockIdx.x * 256 + threadIdx.x;
    int r = gid >> 6, d4 = gid & 63;
    if (r >= mc) return;
    int gr = row0 + r;
    int b, l, p;
    decode_row(gr, b, l, p);
    const float* pos = (l == 0) ? p0_ : (l == 1) ? p1_ : (l == 2) ? p2_ : p3_;
    int HW = lHW[l];
    int d = d4 * 4;
    float4 xv = *(const float4*)(X + (size_t)gr * D_ + d);
    ushort4 o;
    o.x = f2bf(xv.x + pos[(size_t)(b * D_ + d + 0) * HW + p] + le[l * D_ + d + 0]);
    o.y = f2bf(xv.y + pos[(size_t)(b * D_ + d + 1) * HW + p] + le[l * D_ + d + 1]);
    o.z = f2bf(xv.z + pos[(size_t)(b * D_ + d + 2) * HW + p] + le[l * D_ + d + 2]);
    o.w = f2bf(xv.w + pos[(size_t)(b * D_ + d + 3) * HW + p] + le[l * D_ + d + 3]);
    *(ushort4*)(Tq + (size_t)r * D_ + d) = o;
}

// ---------------------------------------------------------------------------
// MFMA bf16 GEMM: C[M,N](ldc) = A[M,K](bf16) @ Wt^T + bias (Wt is [N][K]).
// Tile BM x 128, BK=64, 256 thr = 4 waves 2x2.  global_load_lds width=16,
// linear LDS.  Bijective XCD-chunked swizzle, column-fastest row panels.
// LDS-staged coalesced epilogue (two 64-col halves).
// CB=0: C fp32; CB=1: C bf16; CB=2: C f16.  fp32 residual, relu, dual bias.
// ---------------------------------------------------------------------------
template<int BM, int CB>
__global__ __launch_bounds__(256)
void gemm_b(const ushort_t* __restrict__ A, const ushort_t* __restrict__ Wt,
            const float* __restrict__ bias, const float* __restrict__ bias2,
            int nsplit, const float* __restrict__ Rres,
            void* __restrict__ Cp, int M, int K, int ldc, int relu)
{
    constexpr int AI = BM / 32;            // A-stage insts == A frag count
    constexpr int ES = (CB == 0) ? 4 : 2;  // output element size
    constexpr size_t STAGE_B = (size_t)(BM + 128) * 64 * 2;
    constexpr size_t CT_B = (size_t)BM * 64 * ES;   // per-half C tile
    constexpr size_t LDS_B = (STAGE_B > CT_B) ? STAGE_B : CT_B;
    __shared__ __align__(16) char lds[LDS_B];
    ushort_t* As = (ushort_t*)lds;
    ushort_t* Bs = (ushort_t*)lds + (size_t)BM * 64;
    int t = threadIdx.x;

    // XCD swizzle: orig dispatch id -> contiguous work chunk per XCD.
    int gx = gridDim.x, gy = gridDim.y;
    int nwg = gx * gy;
    int orig = blockIdx.y * gx + blockIdx.x;
    int qn = nwg >> 3, rn = nwg & 7;
    int xcd = orig & 7, idx = orig >> 3;
    int work = (xcd < rn ? xcd * (qn + 1) : rn * (qn + 1) + (xcd - rn) * qn) + idx;
    int bx = work / gy, by = work - bx * gy;   // column-fastest within row panel
    int m0 = bx * BM, n0 = by * 128;

    int w = t >> 6, lane = t & 63;
    int wm = (w & 1) * (BM / 2), wn = (w >> 1) * 64;
    int lm = lane & 15, quad = lane >> 4;
    f32x4 acc[AI][4] = {};

    int srow = lane >> 3;                 // 8 rows per wave-instruction
    int scol = (lane & 7) * 8;
    const ushort_t* Ab = A + (size_t)(m0 + w * (BM / 4) + srow) * K + scol;
    const ushort_t* Bb = Wt + (size_t)(n0 + w * 32 + srow) * K + scol;
    bool mfull = (m0 + BM <= M);

    for (int k0 = 0; k0 < K; k0 += 64) {
        if (mfull) {
            #pragma unroll
            for (int i = 0; i < AI; ++i)
                __builtin_amdgcn_global_load_lds(
                    (const void*)(Ab + (size_t)(i * 8) * K + k0),
                    (void*)&As[(w * (BM / 4) + i * 8) * 64], 16, 0, 0);
        } else {
            #pragma unroll
            for (int i = 0; i < AI; ++i)
                if (m0 + w * (BM / 4) + srow + i * 8 < M)
                    __builtin_amdgcn_global_load_lds(
                        (const void*)(Ab + (size_t)(i * 8) * K + k0),
                        (void*)&As[(w * (BM / 4) + i * 8) * 64], 16, 0, 0);
        }
        #pragma unroll
        for (int i = 0; i < 4; ++i)
            __builtin_amdgcn_global_load_lds(
                (const void*)(Bb + (size_t)(i * 8) * K + k0),
                (void*)&Bs[(w * 32 + i * 8) * 64], 16, 0, 0);
        __syncthreads();
        #pragma unroll
        for (int ks = 0; ks < 64; ks += 32) {
            bf16x8 af[AI], bfr[4];
            #pragma unroll
            for (int i = 0; i < AI; ++i)
                af[i] = *(const bf16x8*)&As[(wm + i * 16 + lm) * 64 + ks + quad * 8];
            #pragma unroll
            for (int j = 0; j < 4; ++j)
                bfr[j] = *(const bf16x8*)&Bs[(wn + j * 16 + lm) * 64 + ks + quad * 8];
            #pragma unroll
            for (int i = 0; i < AI; ++i)
                #pragma unroll
                for (int j = 0; j < 4; ++j)
                    acc[i][j] = __builtin_amdgcn_mfma_f32_16x16x32_bf16(
                        af[i], bfr[j], acc[i][j], 0, 0, 0);
        }
        __syncthreads();
    }

    // ---- LDS-staged coalesced epilogue (two 64-col halves) ----
    constexpr int CHUNKS = (int)(CT_B / 16);       // 16-B chunks per half
    constexpr int CPR = (64 * ES) / 16;            // chunks per row
    constexpr int EPC = 16 / ES;                   // elements per chunk
    int halfsel = w >> 1;                          // this wave's column half
    #pragma unroll
    for (int half = 0; half < 2; ++half) {
        __syncthreads();                           // LDS reuse guard
        if (halfsel == half) {
            #pragma unroll
            for (int i = 0; i < AI; ++i) {
                #pragma unroll
                for (int j = 0; j < 4; ++j) {
                    int col = j * 16 + lm;         // 0..63 within half
                    int gcol = n0 + half * 64 + col;
                    float bc = (gcol < nsplit) ? bias[gcol] : bias2[gcol - nsplit];
                    #pragma unroll
                    for (int r = 0; r < 4; ++r) {
                        int rloc = wm + i * 16 + quad * 4 + r;
                        float v = acc[i][j][r] + bc;
                        if (relu) v = fmaxf(v, 0.f);
                        if (CB == 0) ((float*)lds)[rloc * 64 + col] = v;
                        else if (CB == 1) ((ushort_t*)lds)[rloc * 64 + col] = f2bf(v);
                        else ((ushort_t*)lds)[rloc * 64 + col] = f2h(v);
                    }
                }
            }
        }
        __syncthreads();
        for (int c0 = t; c0 < CHUNKS; c0 += 256) {
            int row = c0 / CPR, cp = c0 - row * CPR;
            int grow = m0 + row;
            if (grow >= M) continue;
            int gcol = n0 + half * 64 + cp * EPC;
            if (CB == 0) {
                float4 f = *(const float4*)(lds + (size_t)c0 * 16);
                if (Rres) {
                    float4 rr = *(const float4*)(Rres + (size_t)grow * ldc + gcol);
                    f.x += rr.x; f.y += rr.y; f.z += rr.z; f.w += rr.w;
                }
                *(float4*)((float*)Cp + (size_t)grow * ldc + gcol) = f;
            } else {
                uint4 val = *(const uint4*)(lds + (size_t)c0 * 16);
                *(uint4*)((ushort_t*)Cp + (size_t)grow * ldc + gcol) = val;
            }
        }
    }
}

// ---------------------------------------------------------------------------
// Fused GEMM + residual + LayerNorm (+ optional next-layer Tq via PL table).
// C = LN(A @ Wt^T + bias + Rres) * g + b  -> X fp32, Xb bf16 (optional),
// Tq bf16 (optional).  Tile 32 x 256 (round-9 geometry: barrier-drain
// amortization via BK=64 beats occupancy — BK=32/16-row regressed 49->79us).
// 4 waves side by side in N, each block owns FULL rows -> per-row mean/var
// via 16-lane shfl + cross-wave LDS reduce.  36 KB LDS -> 4 blocks/CU.
// Epilogue stages the normalized fp32 row-tile in LDS (stride 260) and
// emits all outputs in one coalesced copy.
// ---------------------------------------------------------------------------
__global__ __launch_bounds__(256)
void gemm_ln(const ushort_t* __restrict__ A, const ushort_t* __restrict__ Wt,
             const float* __restrict__ bias, const float* __restrict__ Rres,
             const float* __restrict__ g, const float* __restrict__ b,
             float* __restrict__ Xo, ushort_t* __restrict__ Xb,
             const float* __restrict__ PLf, ushort_t* __restrict__ Tq,
             int M, int K)
{
    __shared__ __align__(16) char lds[36864];
    ushort_t* As = (ushort_t*)lds;                  // [32][64] staging
    ushort_t* Bs = (ushort_t*)(lds + 4096);         // [256][64] staging
    float* Ct   = (float*)lds;                      // [32][260] epilogue tile
    float* psum = (float*)(lds + 33280);            // [4][32][2]
    float* mrs  = (float*)(lds + 34304);            // [32][2]

    int t = threadIdx.x;
    // 1D bijective XCD swizzle
    int nwg = gridDim.x, orig = blockIdx.x;
    int qn = nwg >> 3, rn = nwg & 7;
    int xcd = orig & 7, idx = orig >> 3;
    int work = (xcd < rn ? xcd * (qn + 1) : rn * (qn + 1) + (xcd - rn) * qn) + idx;
    int m0 = work * 32;

    int w = t >> 6, lane = t & 63;
    int lm = lane & 15, quad = lane >> 4;
    int colbase = w * 64;
    f32x4 acc[2][4] = {};

    int srow = lane >> 3;
    int scol = (lane & 7) * 8;
    const ushort_t* Ab = A + (size_t)(m0 + w * 8 + srow) * K + scol;
    const ushort_t* Bb = Wt + (size_t)(colbase + srow) * K + scol;
    bool mfull = (m0 + 32 <= M);

    for (int k0 = 0; k0 < K; k0 += 64) {
        if (mfull) {
            __builtin_amdgcn_global_load_lds((const void*)(Ab + k0),
                (void*)&As[(w * 8) * 64], 16, 0, 0);
        } else {
            if (m0 + w * 8 + srow < M)
                __builtin_amdgcn_global_load_lds((const void*)(Ab + k0),
                    (void*)&As[(w * 8) * 64], 16, 0, 0);
        }
        #pragma unroll
        for (int i = 0; i < 8; ++i)
            __builtin_amdgcn_global_load_lds(
                (const void*)(Bb + (size_t)(i * 8) * K + k0),
                (void*)&Bs[(colbase + i * 8) * 64], 16, 0, 0);
        __syncthreads();
        #pragma unroll
        for (int ks = 0; ks < 64; ks += 32) {
            bf16x8 af[2], bfr[4];
            #pragma unroll
            for (int i = 0; i < 2; ++i)
                af[i] = *(const bf16x8*)&As[(i * 16 + lm) * 64 + ks + quad * 8];
            #pragma unroll
            for (int j = 0; j < 4; ++j)
                bfr[j] = *(const bf16x8*)&Bs[(colbase + j * 16 + lm) * 64 + ks + quad * 8];
            #pragma unroll
            for (int i = 0; i < 2; ++i)
                #pragma unroll
                for (int j = 0; j < 4; ++j)
                    acc[i][j] = __builtin_amdgcn_mfma_f32_16x16x32_bf16(
                        af[i], bfr[j], acc[i][j], 0, 0, 0);
        }
        __syncthreads();
    }

    // v = acc + bias + residual (in place)
    float bcol[4];
    #pragma unroll
    for (int j = 0; j < 4; ++j) bcol[j] = bias[colbase + j * 16 + lm];
    #pragma unroll
    for (int i = 0; i < 2; ++i) {
        #pragma unroll
        for (int r = 0; r < 4; ++r) {
            int grow = m0 + i * 16 + quad * 4 + r;
            bool ok = grow < M;
            #pragma unroll
            for (int j = 0; j < 4; ++j) {
                float res = ok ? Rres[(size_t)grow * 256 + colbase + j * 16 + lm] : 0.f;
                acc[i][j][r] += bcol[j] + res;
            }
        }
    }
    // per-row partial sums: sum over j (in-lane) then over lm (16-lane shfl)
    #pragma unroll
    for (int i = 0; i < 2; ++i) {
        #pragma unroll
        for (int r = 0; r < 4; ++r) {
            float s = acc[i][0][r] + acc[i][1][r] + acc[i][2][r] + acc[i][3][r];
            float q = acc[i][0][r] * acc[i][0][r] + acc[i][1][r] * acc[i][1][r]
                    + acc[i][2][r] * acc[i][2][r] + acc[i][3][r] * acc[i][3][r];
            #pragma unroll
            for (int m = 1; m <= 8; m <<= 1) {
                s += __shfl_xor(s, m, 64);
                q += __shfl_xor(q, m, 64);
            }
            if (lm == 0) {
                int row = i * 16 + quad * 4 + r;
                psum[(w * 32 + row) * 2 + 0] = s;
                psum[(w * 32 + row) * 2 + 1] = q;
            }
        }
    }
    __syncthreads();
    if (t < 32) {
        float s = psum[t * 2] + psum[(32 + t) * 2] + psum[(64 + t) * 2] + psum[(96 + t) * 2];
        float q = psum[t * 2 + 1] + psum[(32 + t) * 2 + 1]
                + psum[(64 + t) * 2 + 1] + psum[(96 + t) * 2 + 1];
        float mean = s * (1.f / 256.f);
        float var = fmaxf(q * (1.f / 256.f) - mean * mean, 0.f);
        mrs[t * 2 + 0] = mean;
        mrs[t * 2 + 1] = rsqrtf(var + 1e-5f);
    }
    __syncthreads();
    // normalize into Ct (stride 260 floats: 16B-aligned, 2-way bank = free)
    float gc[4], bc2[4];
    #pragma unroll
    for (int j = 0; j < 4; ++j) {
        gc[j]  = g[colbase + j * 16 + lm];
        bc2[j] = b[colbase + j * 16 + lm];
    }
    #pragma unroll
    for (int i = 0; i < 2; ++i) {
        #pragma unroll
        for (int r = 0; r < 4; ++r) {
            int row = i * 16 + quad * 4 + r;
            float mean = mrs[row * 2], rs = mrs[row * 2 + 1];
            #pragma unroll
            for (int j = 0; j < 4; ++j)
                Ct[row * 260 + colbase + j * 16 + lm] =
                    (acc[i][j][r] - mean) * rs * gc[j] + bc2[j];
        }
    }
    __syncthreads();
    // coalesced out: X fp32 (+ Xb bf16) (+ Tq bf16 via PL)
    for (int c0 = t; c0 < 32 * 64; c0 += 256) {
        int row = c0 >> 6, cp = c0 & 63;
        int grow = m0 + row;
        if (grow >= M) continue;
        float4 f = *(const float4*)&Ct[row * 260 + cp * 4];
        size_t gbase = (size_t)grow * 256 + cp * 4;
        *(float4*)(Xo + gbase) = f;
        if (Xb) {
            ushort4 ob;
            ob.x = f2bf(f.x); ob.y = f2bf(f.y); ob.z = f2bf(f.z); ob.w = f2bf(f.w);
            *(ushort4*)(Xb + gbase) = ob;
        }
        if (Tq) {
            float4 pl = *(const float4*)(PLf + gbase);
            ushort4 tq;
            tq.x = f2bf(f.x + pl.x); tq.y = f2bf(f.y + pl.y);
            tq.z = f2bf(f.z + pl.z); tq.w = f2bf(f.w + pl.w);
            *(ushort4*)(Tq + gbase) = tq;
        }
    }
}

// ---------------------------------------------------------------------------
// LayerNorm chunk (legacy fallback): X = LN(PRE)*g+b + Xb mirror (+ Tq).
// ---------------------------------------------------------------------------
__global__ __launch_bounds__(256)
void ln_kernel(const float* __restrict__ P, const float* __restrict__ g,
               const float* __restrict__ b, float* __restrict__ Xo,
               ushort_t* __restrict__ Xb,
               const float* __restrict__ PLf,
               const float* __restrict__ p0_, const float* __restrict__ p1_,
               const float* __restrict__ p2_, const float* __restrict__ p3_,
               const float* __restrict__ le, ushort_t* __restrict__ Tq,
               int row0, int mc)
{
    const int lHW[4] = {10000, 2500, 625, 169};
    int wave = threadIdx.x >> 6, lane = threadIdx.x & 63;
    int r = blockIdx.x * 4 + wave;
    if (r >= mc) return;
    const float* x = P + (size_t)r * D_;
    float4 v = *(const float4*)(x + lane * 4);
    float s = v.x + v.y + v.z + v.w;
    float sq = v.x * v.x + v.y * v.y + v.z * v.z + v.w * v.w;
    #pragma unroll
    for (int o = 32; o > 0; o >>= 1) {
        s += __shfl_xor(s, o, 64);
        sq += __shfl_xor(sq, o, 64);
    }
    float mean = s * (1.f / 256.f);
    float var = fmaxf(sq * (1.f / 256.f) - mean * mean, 0.f);
    float rs = rsqrtf(var + 1e-5f);
    float4 gv = *(const float4*)(g + lane * 4);
    float4 bv = *(const float4*)(b + lane * 4);
    float4 o;
    o.x = (v.x - mean) * rs * gv.x + bv.x;
    o.y = (v.y - mean) * rs * gv.y + bv.y;
    o.z = (v.z - mean) * rs * gv.z + bv.z;
    o.w = (v.w - mean) * rs * gv.w + bv.w;
    int gr = row0 + r;
    size_t base = (size_t)gr * D_ + lane * 4;
    *(float4*)(Xo + base) = o;
    ushort4 ob;
    ob.x = f2bf(o.x); ob.y = f2bf(o.y); ob.z = f2bf(o.z); ob.w = f2bf(o.w);
    *(ushort4*)(Xb + base) = ob;
    if (Tq) {
        ushort4 tq;
        if (PLf) {
            float4 pl = *(const float4*)(PLf + base);
            tq.x = f2bf(o.x + pl.x);
            tq.y = f2bf(o.y + pl.y);
            tq.z = f2bf(o.z + pl.z);
            tq.w = f2bf(o.w + pl.w);
        } else {
            int bb, l, p;
            decode_row(gr, bb, l, p);
            const float* pos = (l == 0) ? p0_ : (l == 1) ? p1_ : (l == 2) ? p2_ : p3_;
            int HW = lHW[l];
            int d = lane * 4;
            tq.x = f2bf(o.x + pos[(size_t)(bb * D_ + d + 0) * HW + p] + le[l * D_ + d + 0]);
            tq.y = f2bf(o.y + pos[(size_t)(bb * D_ + d + 1) * HW + p] + le[l * D_ + d + 1]);
            tq.z = f2bf(o.z + pos[(size_t)(bb * D_ + d + 2) * HW + p] + le[l * D_ + d + 2]);
            tq.w = f2bf(o.w + pos[(size_t)(bb * D_ + d + 3) * HW + p] + le[l * D_ + d + 3]);
        }
        *(ushort4*)(Tq + base) = tq;
    }
}

// ---------------------------------------------------------------------------
// Deformable sampling, v3: f16 packed math, 16B gathers, byte-offset
// descriptors, magic-div, XCD-chunked block swizzle, compact weight LDS.
// VAL is ONE contiguous [MROWS][256] **f16** buffer (global-row order).
// LOG row (ld 384, bf16): [0:256) offsets [h][pt][2], [256:384) attn [h][pt]
// ---------------------------------------------------------------------------
__global__ __launch_bounds__(256)
void sample_kernel(const ushort_t* __restrict__ LOG,
                   const ushort_t* __restrict__ VAL,
                   ushort_t* __restrict__ OUT, int row0, int mc)
{
    const int lW[4] = {100, 50, 25, 13};
    const int lS[4] = {0, 10000, 12500, 13125};
    const float invW[4] = {0.01f, 0.02f, 0.04f, 0.076923076923f};
    const unsigned mulM[4] = {5243u, 5243u, 5243u, 5042u};
    const int mulS[4] = {19, 18, 17, 16};

    __shared__ unsigned offs[8 * 8 * 68];   // stride 68 words per (row,head)
    __shared__ unsigned wts[8 * 8 * 36];    // stride 36 words (16B-aligned)

    int tid = threadIdx.x;

    // bijective XCD-chunked swizzle (m204): contiguous row band per XCD
    int nb = gridDim.x, bid = blockIdx.x;
    int xcd = bid & 7, idx = bid >> 3;
    int qc = nb >> 3, rc = nb & 7;
    int swz = (xcd < rc ? xcd * (qc + 1) : rc * (qc + 1) + (xcd - rc) * qc) + idx;
    int brow0 = swz * 8;

    // ---- stage 1: descriptors (4 iterations x 2 rows) ----
    #pragma unroll
    for (int it = 0; it < 4; ++it) {
        int rr = it * 2 + (tid >> 7);
        int j  = tid & 127;
        int h  = j >> 4, pt = j & 15;
        int r  = brow0 + rr;
        bool ok = (r < mc);
        int gr = row0 + (ok ? r : 0);
        int b, lq, p;
        decode_row(gr, b, lq, p);
        unsigned prow = ((unsigned)p * mulM[lq]) >> mulS[lq];   // exact p/W
        int pcol = p - (int)prow * lW[lq];
        float refx = (pcol + 0.5f) * invW[lq];
        float refy = ((float)prow + 0.5f) * invW[lq];

        const ushort_t* lg = LOG + (size_t)r * 384;
        float logit = ok ? u2f(lg[256 + h * 16 + pt]) : 0.f;
        float mx = logit;
        #pragma unroll
        for (int o = 8; o > 0; o >>= 1) mx = fmaxf(mx, __shfl_xor(mx, o, 16));
        float e = __expf(logit - mx);
        float ssum = e;
        #pragma unroll
        for (int o = 8; o > 0; o >>= 1) ssum += __shfl_xor(ssum, o, 16);
        float a = e / ssum;

        int l = pt >> 2;
        int Wl = lW[l];
        float ox = ok ? u2f(lg[h * 32 + pt * 2 + 0]) : 0.f;
        float oy = ok ? u2f(lg[h * 32 + pt * 2 + 1]) : 0.f;
        // (ref + off/W)*W - 0.5 == ref*W + off - 0.5
        float xf = refx * (float)Wl + ox - 0.5f;
        float yf = refy * (float)Wl + oy - 0.5f;
        xf = fmaxf(fminf(xf, 1.0e6f), -1.0e6f);
        yf = fmaxf(fminf(yf, 1.0e6f), -1.0e6f);
        float x0f = floorf(xf), y0f = floorf(yf);
        float fx = xf - x0f, fy = yf - y0f;
        int x0 = (int)x0f, y0 = (int)y0f;
        int x1 = x0 + 1, y1 = y0 + 1;
        int x0c = min(max(x0, 0), Wl - 1), x1c = min(max(x1, 0), Wl - 1);
        int y0c = min(max(y0, 0), Wl - 1), y1c = min(max(y1, 0), Wl - 1);
        float vx0 = (x0 >= 0 && x0 < Wl) ? 1.f : 0.f;
        float vx1 = (x1 >= 0 && x1 < Wl) ? 1.f : 0.f;
        float vy0 = (y0 >= 0 && y0 < Wl) ? 1.f : 0.f;
        float vy1 = (y1 >= 0 && y1 < Wl) ? 1.f : 0.f;
        // byte offsets: pixel stride 512B, head slice 64B
        unsigned base_b = ((unsigned)(b * Q_ + lS[l]) * 256u + (unsigned)(h * 32)) * 2u;
        int di = (rr * 8 + h) * 68 + pt * 4;
        uint4 ov;
        ov.x = base_b + (unsigned)(y0c * Wl + x0c) * 512u;
        ov.y = base_b + (unsigned)(y0c * Wl + x1c) * 512u;
        ov.z = base_b + (unsigned)(y1c * Wl + x0c) * 512u;
        ov.w = base_b + (unsigned)(y1c * Wl + x1c) * 512u;
        *(uint4*)&offs[di] = ov;
        int dw = (rr * 8 + h) * 36 + pt * 2;
        uint2 wv;
        wv.x = packh2(a * (1.f - fx) * (1.f - fy) * vx0 * vy0,
                      a * fx * (1.f - fy) * vx1 * vy0);
        wv.y = packh2(a * (1.f - fx) * fy * vx0 * vy1,
                      a * fx * fy * vx1 * vy1);
        *(uint2*)&wts[dw] = wv;
    }
    __syncthreads();

    // ---- stage 2: 32 threads/row, 16B gathers, pk_fma_f16 ----
    int r8 = tid >> 5;
    int r = brow0 + r8;
    if (r >= mc) return;
    int h = (tid >> 2) & 7;
    int cw = tid & 3;
    int dbase = (r8 * 8 + h) * 68;
    int dbw   = (r8 * 8 + h) * 36;
    const char* Vb = (const char*)VAL + cw * 16;

    __half2 a0 = __float2half2_rn(0.f), a1 = a0, a2 = a0, a3 = a0;
    #pragma unroll
    for (int g = 0; g < 8; ++g) {
        uint4 oA = *(const uint4*)&offs[dbase + g * 8 + 0];
        uint4 oB = *(const uint4*)&offs[dbase + g * 8 + 4];
        uint4 wp = *(const uint4*)&wts[dbw + g * 4];
        uint4 hv[8];
        hv[0] = *(const uint4*)(Vb + oA.x);
        hv[1] = *(const uint4*)(Vb + oA.y);
        hv[2] = *(const uint4*)(Vb + oA.z);
        hv[3] = *(const uint4*)(Vb + oA.w);
        hv[4] = *(const uint4*)(Vb + oB.x);
        hv[5] = *(const uint4*)(Vb + oB.y);
        hv[6] = *(const uint4*)(Vb + oB.z);
        hv[7] = *(const uint4*)(Vb + oB.w);
        __half2 w01 = uash2(wp.x), w23 = uash2(wp.y);
        __half2 w45 = uash2(wp.z), w67 = uash2(wp.w);
        __half2 we[8] = { __low2half2(w01), __high2half2(w01),
                          __low2half2(w23), __high2half2(w23),
                          __low2half2(w45), __high2half2(w45),
                          __low2half2(w67), __high2half2(w67) };
        #pragma unroll
        for (int jj = 0; jj < 8; ++jj) {
            a0 = __hfma2(uash2(hv[jj].x), we[jj], a0);
            a1 = __hfma2(uash2(hv[jj].y), we[jj], a1);
            a2 = __hfma2(uash2(hv[jj].z), we[jj], a2);
            a3 = __hfma2(uash2(hv[jj].w), we[jj], a3);
        }
    }
    float2 f0 = __half22float2(a0), f1 = __half22float2(a1);
    float2 f2v = __half22float2(a2), f3 = __half22float2(a3);
    u16x8 o;
    o[0] = f2bf(f0.x);  o[1] = f2bf(f0.y);
    o[2] = f2bf(f1.x);  o[3] = f2bf(f1.y);
    o[4] = f2bf(f2v.x); o[5] = f2bf(f2v.y);
    o[6] = f2bf(f3.x);  o[7] = f2bf(f3.y);
    *(u16x8*)(OUT + (size_t)r * D_ + h * 32 + cw * 8) = o;
}

extern "C" void kernel_launch(void* const* d_in, const int* in_sizes, int n_in,
                              void* d_out, int out_size, void* d_ws, size_t ws_size,
                              hipStream_t stream)
{
    // setup_inputs() dict order interleaves src/pos (sizes pair up).
    bool interleaved = (in_sizes[0] == in_sizes[1]);
    int si[4], pi[4];
    for (int i = 0; i < 4; ++i) {
        si[i] = interleaved ? 2 * i : i;
        pi[i] = interleaved ? 2 * i + 1 : 4 + i;
    }
    const float* src0 = (const float*)d_in[si[0]];
    const float* src1 = (const float*)d_in[si[1]];
    const float* src2 = (const float*)d_in[si[2]];
    const float* src3 = (const float*)d_in[si[3]];
    const float* pos0 = (const float*)d_in[pi[0]];
    const float* pos1 = (const float*)d_in[pi[1]];
    const float* pos2 = (const float*)d_in[pi[2]];
    const float* pos3 = (const float*)d_in[pi[3]];
    const float* level_embed = (const float*)d_in[8];
    const float* Woff  = (const float*)d_in[9];
    const float* boff  = (const float*)d_in[10];
    const float* Wattn = (const float*)d_in[11];
    const float* battn = (const float*)d_in[12];
    const float* Wv = (const float*)d_in[13];
    const float* bv = (const float*)d_in[14];
    const float* Wo = (const float*)d_in[15];
    const float* bo = (const float*)d_in[16];
    const float* g1 = (const float*)d_in[17];
    const float* b1 = (const float*)d_in[18];
    const float* W1  = (const float*)d_in[19];
    const float* bb1 = (const float*)d_in[20];
    const float* W2  = (const float*)d_in[21];
    const float* bb2 = (const float*)d_in[22];
    const float* g2 = (const float*)d_in[23];
    const float* b2 = (const float*)d_in[24];

    // VAL (f16, [MROWS][256] contiguous) lives in src0's buffer (consumed
    // after flatten; 20.5 MB capacity >= 13.6 MB). Harness restores inputs.
    ushort_t* VAL = (ushort_t*)d_in[si[0]];

    // X (fp32 state) lives in d_out; the final LN writes the output in place.
    float* X = (float*)d_out;

    const int WV_T = 98304, WO_T = 163840, W1_T = 229376, W2_T = 491520;
    const size_t WB_ELEMS = 753664;   // Woff^T+Wattn^T combined block at 0

    // ws = WB (1.507 MB) + Xb bf16 mirror (13.6 MB) + chunk region R +
    // optional PL fp32 table (27.2 MB, gated on ws_size).
    const int cand[9] = {1, 2, 4, 8, 16, 32, 64, 128, 256};
    int NC = 256;
    for (int i = 0; i < 9; ++i) {
        int rc = (MROWS + cand[i] - 1) / cand[i];
        size_t need = WB_ELEMS * 2 + MD * 2 + (size_t)rc * 3072 + 1024;
        if (need <= ws_size) { NC = cand[i]; break; }
    }
    const int RC = (MROWS + NC - 1) / NC;
    const bool fused_tq = (NC == 1);
    const size_t base_need = WB_ELEMS * 2 + MD * 2 + (size_t)RC * 3072 + 1024;
    const bool use_pl = fused_tq && (base_need + MD * 4 <= ws_size);
    const bool full_fuse = use_pl;   // gemm_ln path (needs PL for Tq emission)

    ushort_t* WBl  = (ushort_t*)d_ws;
    ushort_t* Xb   = (ushort_t*)((char*)d_ws + WB_ELEMS * 2);
    char* Rbase    = (char*)d_ws + WB_ELEMS * 2 + MD * 2;
    ushort_t* Tqu  = (ushort_t*)Rbase;
    ushort_t* LOGc = (ushort_t*)(Rbase + (size_t)RC * 512);
    float* PRE     = (float*)(Rbase + (size_t)RC * 2048);
    ushort_t* H1u  = (ushort_t*)Rbase;
    // In full_fuse, next-layer Tq goes to the (dead) PRE region, NOT Tqu:
    // fused FFN2 reads H1u (which overlays Tqu) while emitting Tq.
    ushort_t* Tq2  = (ushort_t*)(Rbase + (size_t)RC * 2048);
    float* PLf     = use_pl ? (float*)(Rbase + (size_t)RC * 3072) : nullptr;

    flatten_kernel<<<dim3(313, 8, 8), dim3(32, 8), 0, stream>>>(
        src0, src1, src2, src3, pos0, pos1, pos2, pos3, level_embed,
        X, Xb, fused_tq ? Tqu : nullptr);
    if (use_pl)
        pl_kernel<<<dim3(313, 8, 8), dim3(32, 8), 0, stream>>>(
            pos0, pos1, pos2, pos3, level_embed, PLf);

    const int BIG = 1 << 30;
    const int GLN = (MROWS + 31) / 32;

    for (int l = 0; l < NLAYERS_; ++l) {
        const float* Woff_l  = Woff  + (size_t)l * D_ * 256;
        const float* boff_l  = boff  + (size_t)l * 256;
        const float* Wattn_l = Wattn + (size_t)l * D_ * 128;
        const float* battn_l = battn + (size_t)l * 128;
        const float* Wv_l = Wv + (size_t)l * D_ * D_;
        const float* bv_l = bv + (size_t)l * D_;
        const float* Wo_l = Wo + (size_t)l * D_ * D_;
        const float* bo_l = bo + (size_t)l * D_;
        const float* g1_l = g1 + (size_t)l * D_;
        const float* b1_l = b1 + (size_t)l * D_;
        const float* W1_l  = W1  + (size_t)l * D_ * 1024;
        const float* bb1_l = bb1 + (size_t)l * 1024;
        const float* W2_l  = W2  + (size_t)l * 1024 * D_;
        const float* bb2_l = bb2 + (size_t)l * D_;
        const float* g2_l = g2 + (size_t)l * D_;
        const float* b2_l = b2 + (size_t)l * D_;

        wconv_kernel<<<dim3(256, 6), dim3(32, 8), 0, stream>>>(
            Woff_l, Wattn_l, Wv_l, Wo_l, W1_l, W2_l, WBl);

        // VAL = X @ Wv + bv : thin-N (256) -> BM=64, f16 output
        gemm_b<64, 2><<<dim3((MROWS + 63) / 64, 2), 256, 0, stream>>>(
            Xb, WBl + WV_T, bv_l, nullptr, BIG, nullptr, VAL, MROWS, 256, 256, 0);

        // attention, chunked
        for (int c = 0; c < NC; ++c) {
            int row0 = c * RC;
            int mc = MROWS - row0; if (mc > RC) mc = RC;
            if (mc <= 0) break;
            if (!fused_tq)
                qmake_kernel<<<(mc * 64 + 255) / 256, 256, 0, stream>>>(
                    X, pos0, pos1, pos2, pos3, level_embed, Tqu, row0, mc);
            // query location: layer 0 from flatten (Tqu); later layers from
            // the fused ln2 (Tq2) in full_fuse mode, else Tqu.
            const ushort_t* Qcur = (full_fuse && l > 0) ? Tq2 : Tqu;
            gemm_b<64, 1><<<dim3((mc + 63) / 64, 3), 256, 0, stream>>>(
                Qcur, WBl, boff_l, battn_l, 256, nullptr, LOGc, mc, 256, 384, 0);
            sample_kernel<<<(mc + 7) / 8, 256, 0, stream>>>(
                LOGc, VAL, Tqu, row0, mc);
            if (full_fuse) {
                // Wo GEMM + residual + ln1 fused (no Tq)
                gemm_ln<<<GLN, 256, 0, stream>>>(
                    Tqu, WBl + WO_T, bo_l, X, g1_l, b1_l, X, Xb,
                    nullptr, nullptr, MROWS, 256);
            } else {
                gemm_b<64, 0><<<dim3((mc + 63) / 64, 2), 256, 0, stream>>>(
                    Tqu, WBl + WO_T, bo_l, nullptr, BIG,
                    X + (size_t)row0 * D_, PRE, mc, 256, 256, 0);
                ln_kernel<<<(mc + 3) / 4, 256, 0, stream>>>(
                    PRE, g1_l, b1_l, X, Xb, nullptr,
                    pos0, pos1, pos2, pos3, level_embed, (ushort_t*)nullptr,
                    row0, mc);
            }
        }

        // FFN, chunked (H1u overlays Tqu/LOG; Tq2/PRE disjoint)
        for (int c = 0; c < NC; ++c) {
            int row0 = c * RC;
            int mc = MROWS - row0; if (mc > RC) mc = RC;
            if (mc <= 0) break;
            float* Xc = X + (size_t)row0 * D_;
            // FFN1: N=1024 wide -> keep BM=128 (grid already large)
            gemm_b<128, 1><<<dim3((mc + 127) / 128, 8), 256, 0, stream>>>(
                Xb + (size_t)row0 * D_, WBl + W1_T, bb1_l, nullptr, BIG,
                nullptr, H1u, mc, 256, 1024, 1);
            if (full_fuse) {
                // FFN2 + residual + ln2 fused; emits next-layer Tq into Tq2.
                // Last layer: Xb and Tq are dead -> skip both mirror writes.
                bool last = (l == NLAYERS_ - 1);
                ushort_t* TqNext = last ? nullptr : Tq2;
                gemm_ln<<<GLN, 256, 0, stream>>>(
                    H1u, WBl + W2_T, bb2_l, X, g2_l, b2_l, X,
                    last ? nullptr : Xb, PLf, TqNext, MROWS, 1024);
            } else {
                gemm_b<64, 0><<<dim3((mc + 63) / 64, 2), 256, 0, stream>>>(
                    H1u, WBl + W2_T, bb2_l, nullptr, BIG, Xc, PRE, mc, 1024, 256, 0);
                ushort_t* TqNext = (fused_tq && l < NLAYERS_ - 1) ? Tqu : nullptr;
                ln_kernel<<<(mc + 3) / 4, 256, 0, stream>>>(
                    PRE, g2_l, b2_l, X, Xb, PLf,
                    pos0, pos1, pos2, pos3, level_embed, TqNext,
                    row0, mc);
            }
        }
    }
}